// Round 4
// baseline (505.853 us; speedup 1.0000x reference)
//
#include <hip/hip_runtime.h>

#define INV_SQRT2 0.70710678118654752440f

typedef __attribute__((ext_vector_type(8))) short bf16x8;   // 8 bf16 = 4 VGPRs (MFMA A/B frag)
typedef __attribute__((ext_vector_type(4))) float f32x4;    // MFMA C/D frag / native 16B vector
typedef __attribute__((ext_vector_type(8))) unsigned short u16x8;  // 16B bf16 load

__device__ __forceinline__ unsigned short f32_to_bf16_rne(float f) {
    unsigned int u = __builtin_bit_cast(unsigned int, f);
    u += 0x7FFFu + ((u >> 16) & 1u);       // round-to-nearest-even
    return (unsigned short)(u >> 16);
}
__device__ __forceinline__ float bf16_to_f32(unsigned short h) {
    return __builtin_bit_cast(float, ((unsigned int)h) << 16);
}

// ---------------------------------------------------------------------------
// Phase 0: convert [Wsrc | Wdst] fp32 -> bf16 into Wb (8192 elems). ~1 us.
// x is no longer staged: transform converts it in-register.
// ---------------------------------------------------------------------------
__global__ __launch_bounds__(256) void convert_w_k(
    const float* __restrict__ Wsrc,
    const float* __restrict__ Wdst,
    unsigned short* __restrict__ Wb)
{
    int t = blockIdx.x * 256 + threadIdx.x;   // 1024 threads, 8 elems each
    if (t >= 1024) return;
    int base = t * 8;

    const float* sp = (base < 4096) ? (Wsrc + base) : (Wdst + (base - 4096));
    unsigned short* dp = Wb + base;

    float4 a = ((const float4*)sp)[0];
    float4 b = ((const float4*)sp)[1];
    uint4 o;
    o.x = (unsigned)f32_to_bf16_rne(a.x) | ((unsigned)f32_to_bf16_rne(a.y) << 16);
    o.y = (unsigned)f32_to_bf16_rne(a.z) | ((unsigned)f32_to_bf16_rne(a.w) << 16);
    o.z = (unsigned)f32_to_bf16_rne(b.x) | ((unsigned)f32_to_bf16_rne(b.y) << 16);
    o.w = (unsigned)f32_to_bf16_rne(b.z) | ((unsigned)f32_to_bf16_rne(b.w) << 16);
    *((uint4*)dp) = o;
}

// ---------------------------------------------------------------------------
// Phase 1: h[row][0:128] = (x[row] . W[n]) * INV_SQRT2 via bf16 MFMA.
// Reads fp32 x directly, converts A-frags in-register (same RNE as before,
// bitwise-identical result; saves the xb round-trip through HBM/L2).
// ---------------------------------------------------------------------------
__global__ __launch_bounds__(256) void transform_mfma_k(
    const float* __restrict__ x,             // (rows, 64) fp32
    const unsigned short* __restrict__ Wb,   // (128, 64) bf16  [Wsrc;Wdst]
    unsigned short* __restrict__ hb,         // (rows, 128) bf16
    int rows)
{
    int wave = (blockIdx.x * 256 + threadIdx.x) >> 6;
    int lane = threadIdx.x & 63;
    int row_tiles = (rows + 15) >> 4;
    if (wave >= row_tiles) return;

    int m    = lane & 15;
    int quad = lane >> 4;

    int arow_i = wave * 16 + m;
    if (arow_i >= rows) arow_i = rows - 1;          // clamp load (store is guarded)
    const float4* arow = (const float4*)(x + (size_t)arow_i * 64);
    // a0: k = quad*8 + j (j<8); a1: k = 32 + quad*8 + j
    float4 f0 = arow[quad * 2];
    float4 f1 = arow[quad * 2 + 1];
    float4 f2 = arow[8 + quad * 2];
    float4 f3 = arow[8 + quad * 2 + 1];

    bf16x8 a0, a1;
    a0[0] = (short)f32_to_bf16_rne(f0.x);
    a0[1] = (short)f32_to_bf16_rne(f0.y);
    a0[2] = (short)f32_to_bf16_rne(f0.z);
    a0[3] = (short)f32_to_bf16_rne(f0.w);
    a0[4] = (short)f32_to_bf16_rne(f1.x);
    a0[5] = (short)f32_to_bf16_rne(f1.y);
    a0[6] = (short)f32_to_bf16_rne(f1.z);
    a0[7] = (short)f32_to_bf16_rne(f1.w);
    a1[0] = (short)f32_to_bf16_rne(f2.x);
    a1[1] = (short)f32_to_bf16_rne(f2.y);
    a1[2] = (short)f32_to_bf16_rne(f2.z);
    a1[3] = (short)f32_to_bf16_rne(f2.w);
    a1[4] = (short)f32_to_bf16_rne(f3.x);
    a1[5] = (short)f32_to_bf16_rne(f3.y);
    a1[6] = (short)f32_to_bf16_rne(f3.z);
    a1[7] = (short)f32_to_bf16_rne(f3.w);

    f32x4 acc[8];
#pragma unroll
    for (int ct = 0; ct < 8; ++ct) {
        int n = ct * 16 + m;
        const bf16x8* brow = (const bf16x8*)(Wb + (size_t)n * 64);
        bf16x8 b0 = brow[quad];
        bf16x8 b1 = brow[4 + quad];
        f32x4 c = {0.f, 0.f, 0.f, 0.f};
        c = __builtin_amdgcn_mfma_f32_16x16x32_bf16(a0, b0, c, 0, 0, 0);
        c = __builtin_amdgcn_mfma_f32_16x16x32_bf16(a1, b1, c, 0, 0, 0);
        acc[ct] = c;
    }

    // C/D layout: col = lane&15, row = quad*4 + r
#pragma unroll
    for (int ct = 0; ct < 8; ++ct) {
#pragma unroll
        for (int r = 0; r < 4; ++r) {
            int orow = wave * 16 + quad * 4 + r;
            if (orow < rows) {
                hb[(size_t)orow * 128 + ct * 16 + m] =
                    f32_to_bf16_rne(acc[ct][r] * INV_SQRT2);
            }
        }
    }
}

// ---------------------------------------------------------------------------
// Phase 2: out[b][e][:] = hs_row + hd_row (scale pre-folded).
// 8 lanes/edge, TWO edges and BOTH batches per thread:
//  - 8 independent 16B gathered loads in flight per thread (latency-bound
//    path: maximize requests outstanding, not request size),
//  - int2 index loads (half the redundant index traffic),
//  - nontemporal 16B stores keep the 409.6 MB output stream from evicting
//    the 25.6 MB hb table (reads are ~16x-reused, want it cache-resident).
// ---------------------------------------------------------------------------
__device__ __forceinline__ void sum_store(const u16x8 a, const u16x8 b,
                                          f32x4* __restrict__ out, size_t o4)
{
    f32x4 lo, hi;
    lo[0] = bf16_to_f32(a[0]) + bf16_to_f32(b[0]);
    lo[1] = bf16_to_f32(a[1]) + bf16_to_f32(b[1]);
    lo[2] = bf16_to_f32(a[2]) + bf16_to_f32(b[2]);
    lo[3] = bf16_to_f32(a[3]) + bf16_to_f32(b[3]);
    hi[0] = bf16_to_f32(a[4]) + bf16_to_f32(b[4]);
    hi[1] = bf16_to_f32(a[5]) + bf16_to_f32(b[5]);
    hi[2] = bf16_to_f32(a[6]) + bf16_to_f32(b[6]);
    hi[3] = bf16_to_f32(a[7]) + bf16_to_f32(b[7]);
    __builtin_nontemporal_store(lo, &out[o4]);
    __builtin_nontemporal_store(hi, &out[o4 + 1]);
}

__global__ __launch_bounds__(256) void gather_k(
    const unsigned short* __restrict__ hb,   // (B*N, 128) bf16
    const int* __restrict__ src,
    const int* __restrict__ dst,
    f32x4* __restrict__ out,
    int E, int N)
{
    int t = blockIdx.x * 256 + threadIdx.x;  // [0, E*4)
    if (t >= E * 4) return;
    int p = t >> 3;            // edge pair index
    int c = t & 7;
    int e0 = p * 2;            // handles edges e0, e0+1

    int2 sp = *(const int2*)(src + e0);
    int2 dp = *(const int2*)(dst + e0);

    const unsigned short* h0 = hb;                       // batch 0 rows
    const unsigned short* h1 = hb + (size_t)N * 128;     // batch 1 rows
    const int off = c * 8;

    // 8 independent gathered 16B loads, issued back-to-back
    u16x8 us0a = *(const u16x8*)(h0 + (size_t)sp.x * 128 + off);
    u16x8 ud0a = *(const u16x8*)(h0 + (size_t)dp.x * 128 + 64 + off);
    u16x8 us1a = *(const u16x8*)(h1 + (size_t)sp.x * 128 + off);
    u16x8 ud1a = *(const u16x8*)(h1 + (size_t)dp.x * 128 + 64 + off);
    u16x8 us0b = *(const u16x8*)(h0 + (size_t)sp.y * 128 + off);
    u16x8 ud0b = *(const u16x8*)(h0 + (size_t)dp.y * 128 + 64 + off);
    u16x8 us1b = *(const u16x8*)(h1 + (size_t)sp.y * 128 + off);
    u16x8 ud1b = *(const u16x8*)(h1 + (size_t)dp.y * 128 + 64 + off);

    size_t c2 = (size_t)(c * 2);
    sum_store(us0a, ud0a, out, (size_t)e0 * 16 + c2);              // e0, b=0
    sum_store(us1a, ud1a, out, ((size_t)E + e0) * 16 + c2);        // e0, b=1
    sum_store(us0b, ud0b, out, (size_t)(e0 + 1) * 16 + c2);        // e1, b=0
    sum_store(us1b, ud1b, out, ((size_t)E + e0 + 1) * 16 + c2);    // e1, b=1
}

// ---------------------------------------------------------------------------
// Fallback (ws too small): fused per-edge fp32 compute. Correct, slow.
// ---------------------------------------------------------------------------
__global__ __launch_bounds__(256) void fused_fallback_k(
    const float* __restrict__ x,
    const int* __restrict__ src,
    const int* __restrict__ dst,
    const float* __restrict__ Wsrc,
    const float* __restrict__ Wdst,
    float* __restrict__ out,
    int E, int N)
{
    int t = blockIdx.x * 256 + threadIdx.x;
    if (t >= E * 64) return;
    int o = t & 63;
    int e = t >> 6;
    int b = blockIdx.y;

    const float* xs = x + ((size_t)(b * N + src[e])) * 64;
    const float* xd = x + ((size_t)(b * N + dst[e])) * 64;
    const float* ws = Wsrc + o * 64;
    const float* wd = Wdst + o * 64;
    float acc = 0.0f;
#pragma unroll
    for (int k = 0; k < 64; ++k) {
        acc = fmaf(xs[k], ws[k], acc);
        acc = fmaf(xd[k], wd[k], acc);
    }
    out[((size_t)b * E + e) * 64 + o] = acc * INV_SQRT2;
}

extern "C" void kernel_launch(void* const* d_in, const int* in_sizes, int n_in,
                              void* d_out, int out_size, void* d_ws, size_t ws_size,
                              hipStream_t stream)
{
    const float* x    = (const float*)d_in[0];
    const int*   src  = (const int*)d_in[1];
    const int*   dst  = (const int*)d_in[2];
    const float* Wsrc = (const float*)d_in[3];
    const float* Wdst = (const float*)d_in[4];
    float* out = (float*)d_out;

    const int E = in_sizes[1];
    const long long xsz = in_sizes[0];
    const int B = (int)((long long)out_size / ((long long)E * 64));  // 2
    const int N = (int)(xsz / ((long long)B * 64));                  // 50000
    const int rows = B * N;                                          // 100000

    // ws layout: Wb (128*64 bf16) | hb (rows*128 bf16)
    const size_t wb_elems = 128 * 64;
    const size_t hb_elems = (size_t)rows * 128;
    const size_t need = (wb_elems + hb_elems) * sizeof(unsigned short);

    if (ws_size >= need && B == 2 && (E & 1) == 0) {
        unsigned short* Wb = (unsigned short*)d_ws;
        unsigned short* hb = Wb + wb_elems;

        convert_w_k<<<4, 256, 0, stream>>>(Wsrc, Wdst, Wb);

        int row_tiles = (rows + 15) >> 4;            // waves needed
        int g1 = (row_tiles + 3) / 4;                // 4 waves/block
        transform_mfma_k<<<g1, 256, 0, stream>>>(x, Wb, hb, rows);

        int g2 = (E * 4 + 255) / 256;
        gather_k<<<g2, 256, 0, stream>>>(hb, src, dst, (f32x4*)out, E, N);
    } else {
        dim3 g((E * 64 + 255) / 256, B);
        fused_fallback_k<<<g, 256, 0, stream>>>(x, src, dst, Wsrc, Wdst, out, E, N);
    }
}

// Round 6
// 496.609 us; speedup vs baseline: 1.0186x; 1.0186x over previous
//
#include <hip/hip_runtime.h>

#define INV_SQRT2 0.70710678118654752440f

typedef __attribute__((ext_vector_type(8))) short bf16x8;   // 8 bf16 = 4 VGPRs (MFMA A/B frag)
typedef __attribute__((ext_vector_type(4))) float f32x4;    // MFMA C/D frag / native 16B vector
typedef __attribute__((ext_vector_type(8))) unsigned short u16x8;  // 16B bf16 load

__device__ __forceinline__ unsigned short f32_to_bf16_rne(float f) {
    unsigned int u = __builtin_bit_cast(unsigned int, f);
    u += 0x7FFFu + ((u >> 16) & 1u);       // round-to-nearest-even
    return (unsigned short)(u >> 16);
}
__device__ __forceinline__ float bf16_to_f32(unsigned short h) {
    return __builtin_bit_cast(float, ((unsigned int)h) << 16);
}

// ---------------------------------------------------------------------------
// Phase 0: convert [Wsrc | Wdst] fp32 -> bf16 into Wb (8192 elems). ~1 us.
// ---------------------------------------------------------------------------
__global__ __launch_bounds__(256) void convert_w_k(
    const float* __restrict__ Wsrc,
    const float* __restrict__ Wdst,
    unsigned short* __restrict__ Wb)
{
    int t = blockIdx.x * 256 + threadIdx.x;   // 1024 threads, 8 elems each
    if (t >= 1024) return;
    int base = t * 8;

    const float* sp = (base < 4096) ? (Wsrc + base) : (Wdst + (base - 4096));
    unsigned short* dp = Wb + base;

    float4 a = ((const float4*)sp)[0];
    float4 b = ((const float4*)sp)[1];
    uint4 o;
    o.x = (unsigned)f32_to_bf16_rne(a.x) | ((unsigned)f32_to_bf16_rne(a.y) << 16);
    o.y = (unsigned)f32_to_bf16_rne(a.z) | ((unsigned)f32_to_bf16_rne(a.w) << 16);
    o.z = (unsigned)f32_to_bf16_rne(b.x) | ((unsigned)f32_to_bf16_rne(b.y) << 16);
    o.w = (unsigned)f32_to_bf16_rne(b.z) | ((unsigned)f32_to_bf16_rne(b.w) << 16);
    *((uint4*)dp) = o;
}

// ---------------------------------------------------------------------------
// Phase 1: MFMA transform, fp32 x read directly (in-register bf16 convert).
// OUTPUT LAYOUT ht[n] = [hs_b0(64) | hs_b1(64) | hd_b0(64) | hd_b1(64)]
// (512 B per node): both batches of a node's h-vector are ADJACENT, so the
// gather reads 2 random 256B segments per edge instead of 4 random 128B.
// ---------------------------------------------------------------------------
__global__ __launch_bounds__(256) void transform_mfma_k(
    const float* __restrict__ x,             // (rows = B*N, 64) fp32
    const unsigned short* __restrict__ Wb,   // (128, 64) bf16  [Wsrc;Wdst]
    unsigned short* __restrict__ ht,         // (N, 2seg, 2b, 64) bf16
    int rows, int N)
{
    int wave = (blockIdx.x * 256 + threadIdx.x) >> 6;
    int lane = threadIdx.x & 63;
    int row_tiles = (rows + 15) >> 4;
    if (wave >= row_tiles) return;

    int m    = lane & 15;
    int quad = lane >> 4;

    int arow_i = wave * 16 + m;
    if (arow_i >= rows) arow_i = rows - 1;          // clamp load (store is guarded)
    const float4* arow = (const float4*)(x + (size_t)arow_i * 64);
    float4 f0 = arow[quad * 2];
    float4 f1 = arow[quad * 2 + 1];
    float4 f2 = arow[8 + quad * 2];
    float4 f3 = arow[8 + quad * 2 + 1];

    bf16x8 a0, a1;
    a0[0] = (short)f32_to_bf16_rne(f0.x);
    a0[1] = (short)f32_to_bf16_rne(f0.y);
    a0[2] = (short)f32_to_bf16_rne(f0.z);
    a0[3] = (short)f32_to_bf16_rne(f0.w);
    a0[4] = (short)f32_to_bf16_rne(f1.x);
    a0[5] = (short)f32_to_bf16_rne(f1.y);
    a0[6] = (short)f32_to_bf16_rne(f1.z);
    a0[7] = (short)f32_to_bf16_rne(f1.w);
    a1[0] = (short)f32_to_bf16_rne(f2.x);
    a1[1] = (short)f32_to_bf16_rne(f2.y);
    a1[2] = (short)f32_to_bf16_rne(f2.z);
    a1[3] = (short)f32_to_bf16_rne(f2.w);
    a1[4] = (short)f32_to_bf16_rne(f3.x);
    a1[5] = (short)f32_to_bf16_rne(f3.y);
    a1[6] = (short)f32_to_bf16_rne(f3.z);
    a1[7] = (short)f32_to_bf16_rne(f3.w);

    f32x4 acc[8];
#pragma unroll
    for (int ct = 0; ct < 8; ++ct) {
        int n = ct * 16 + m;
        const bf16x8* brow = (const bf16x8*)(Wb + (size_t)n * 64);
        bf16x8 b0 = brow[quad];
        bf16x8 b1 = brow[4 + quad];
        f32x4 c = {0.f, 0.f, 0.f, 0.f};
        c = __builtin_amdgcn_mfma_f32_16x16x32_bf16(a0, b0, c, 0, 0, 0);
        c = __builtin_amdgcn_mfma_f32_16x16x32_bf16(a1, b1, c, 0, 0, 0);
        acc[ct] = c;
    }

    // C/D layout: col = lane&15 (within tile ct), row = quad*4 + r
#pragma unroll
    for (int ct = 0; ct < 8; ++ct) {
        int col = ct * 16 + m;      // [0,128): <64 = hs, >=64 = hd
        int seg = col >> 6;
        int cc  = col & 63;
#pragma unroll
        for (int r = 0; r < 4; ++r) {
            int orow = wave * 16 + quad * 4 + r;
            if (orow < rows) {
                int b = (orow >= N) ? 1 : 0;
                int n = orow - b * N;
                ht[(size_t)n * 256 + seg * 128 + b * 64 + cc] =
                    f32_to_bf16_rne(acc[ct][r] * INV_SQRT2);
            }
        }
    }
}

// ---------------------------------------------------------------------------
// Phase 2: out[b][e][:] = hs_row + hd_row. 16 lanes/edge (b = lane>>3),
// 2 edges/thread. Per edge: TWO random 256B segments (src-half, dst-half),
// half the scattered transactions of the previous 4x128B layout.
// nt stores keep the 409.6 MB output stream out of L2.
// ---------------------------------------------------------------------------
__device__ __forceinline__ void sum_store(const u16x8 a, const u16x8 b,
                                          f32x4* __restrict__ out, size_t o4)
{
    f32x4 lo, hi;
    lo[0] = bf16_to_f32(a[0]) + bf16_to_f32(b[0]);
    lo[1] = bf16_to_f32(a[1]) + bf16_to_f32(b[1]);
    lo[2] = bf16_to_f32(a[2]) + bf16_to_f32(b[2]);
    lo[3] = bf16_to_f32(a[3]) + bf16_to_f32(b[3]);
    hi[0] = bf16_to_f32(a[4]) + bf16_to_f32(b[4]);
    hi[1] = bf16_to_f32(a[5]) + bf16_to_f32(b[5]);
    hi[2] = bf16_to_f32(a[6]) + bf16_to_f32(b[6]);
    hi[3] = bf16_to_f32(a[7]) + bf16_to_f32(b[7]);
    __builtin_nontemporal_store(lo, &out[o4]);
    __builtin_nontemporal_store(hi, &out[o4 + 1]);
}

__global__ __launch_bounds__(256) void gather_k(
    const unsigned short* __restrict__ ht,   // (N, 512B) node-fused layout
    const int* __restrict__ src,
    const int* __restrict__ dst,
    f32x4* __restrict__ out,
    int E, int N)
{
    int t = blockIdx.x * 256 + threadIdx.x;  // [0, E*8)
    if (t >= E * 8) return;
    int p = t >> 4;            // edge-pair index
    int c = t & 15;            // b = c>>3, col-block = (c&7)*8
    int e0 = p * 2;

    int2 sp = *(const int2*)(src + e0);
    int2 dp = *(const int2*)(dst + e0);

    int b    = c >> 3;
    int cc   = (c & 7) * 8;
    int soff = b * 64 + cc;          // within src segment [hs_b0|hs_b1]
    int doff = 128 + b * 64 + cc;    // within dst segment [hd_b0|hd_b1]

    // 4 independent gathered 16B loads (2 edges x {src,dst})
    u16x8 sa = *(const u16x8*)(ht + (size_t)sp.x * 256 + soff);
    u16x8 da = *(const u16x8*)(ht + (size_t)dp.x * 256 + doff);
    u16x8 sb = *(const u16x8*)(ht + (size_t)sp.y * 256 + soff);
    u16x8 db = *(const u16x8*)(ht + (size_t)dp.y * 256 + doff);

    size_t oa = (((size_t)b * E + e0) * 64 + cc) >> 2;        // f32x4 index
    sum_store(sa, da, out, oa);
    size_t ob = (((size_t)b * E + e0 + 1) * 64 + cc) >> 2;
    sum_store(sb, db, out, ob);
}

// ---------------------------------------------------------------------------
// Fallback (ws too small): fused per-edge fp32 compute. Correct, slow.
// ---------------------------------------------------------------------------
__global__ __launch_bounds__(256) void fused_fallback_k(
    const float* __restrict__ x,
    const int* __restrict__ src,
    const int* __restrict__ dst,
    const float* __restrict__ Wsrc,
    const float* __restrict__ Wdst,
    float* __restrict__ out,
    int E, int N)
{
    int t = blockIdx.x * 256 + threadIdx.x;
    if (t >= E * 64) return;
    int o = t & 63;
    int e = t >> 6;
    int b = blockIdx.y;

    const float* xs = x + ((size_t)(b * N + src[e])) * 64;
    const float* xd = x + ((size_t)(b * N + dst[e])) * 64;
    const float* ws = Wsrc + o * 64;
    const float* wd = Wdst + o * 64;
    float acc = 0.0f;
#pragma unroll
    for (int k = 0; k < 64; ++k) {
        acc = fmaf(xs[k], ws[k], acc);
        acc = fmaf(xd[k], wd[k], acc);
    }
    out[((size_t)b * E + e) * 64 + o] = acc * INV_SQRT2;
}

extern "C" void kernel_launch(void* const* d_in, const int* in_sizes, int n_in,
                              void* d_out, int out_size, void* d_ws, size_t ws_size,
                              hipStream_t stream)
{
    const float* x    = (const float*)d_in[0];
    const int*   src  = (const int*)d_in[1];
    const int*   dst  = (const int*)d_in[2];
    const float* Wsrc = (const float*)d_in[3];
    const float* Wdst = (const float*)d_in[4];
    float* out = (float*)d_out;

    const int E = in_sizes[1];
    const long long xsz = in_sizes[0];
    const int B = (int)((long long)out_size / ((long long)E * 64));  // 2
    const int N = (int)(xsz / ((long long)B * 64));                  // 50000
    const int rows = B * N;                                          // 100000

    // ws layout: Wb (128*64 bf16) | ht (N*256 bf16, node-fused layout)
    const size_t wb_elems = 128 * 64;
    const size_t ht_elems = (size_t)N * 256;
    const size_t need = (wb_elems + ht_elems) * sizeof(unsigned short);

    if (ws_size >= need && B == 2 && (E & 1) == 0) {
        unsigned short* Wb = (unsigned short*)d_ws;
        unsigned short* ht = Wb + wb_elems;

        convert_w_k<<<4, 256, 0, stream>>>(Wsrc, Wdst, Wb);

        int row_tiles = (rows + 15) >> 4;            // waves needed
        int g1 = (row_tiles + 3) / 4;                // 4 waves/block
        transform_mfma_k<<<g1, 256, 0, stream>>>(x, Wb, ht, rows, N);

        int g2 = (E * 8 + 255) / 256;
        gather_k<<<g2, 256, 0, stream>>>(ht, src, dst, (f32x4*)out, E, N);
    } else {
        dim3 g((E * 64 + 255) / 256, B);
        fused_fallback_k<<<g, 256, 0, stream>>>(x, src, dst, Wsrc, Wdst, out, E, N);
    }
}